// Round 6
// baseline (168.860 us; speedup 1.0000x reference)
//
#include <hip/hip_runtime.h>
#include <hip/hip_bf16.h>
#include <stdint.h>

#define BB 32
#define IC 128
#define OC 128
#define HH 56
#define WW 56
#define ZD 512
#define NRS 9
#define OI (OC*IC)            // 16384
#define WROWS (OI*NRS)        // 147456
#define WDIM 58               // conv LDS width index u = w_in+1, 0..57

typedef float  f32x4  __attribute__((ext_vector_type(4)));
typedef short  bf16x8 __attribute__((ext_vector_type(8)));

static __device__ __forceinline__ short f2bf(float f) {
    uint32_t u = __float_as_uint(f);
    uint32_t r = (u + 0x7fffu + ((u >> 16) & 1u)) >> 16;
    return (short)r;
}
static __device__ __forceinline__ short f2bf_hw(float f) {
    __hip_bfloat16 h = __float2bfloat16(f);
    return *reinterpret_cast<short*>(&h);
}
static __device__ __forceinline__ float bf2f(short s) {
    uint32_t u = ((uint32_t)(uint16_t)s) << 16;
    return __uint_as_float(u);
}
static __device__ __forceinline__ void gll16(const void* g, void* l) {
    __builtin_amdgcn_global_load_lds(
        (const __attribute__((address_space(1))) uint32_t*)g,
        (__attribute__((address_space(3))) uint32_t*)l, 16, 0, 0);
}

// ---------------------------------------------------------------------------
// Kernel 1 (v6): head, reg-staged streaming (plain global_load -> VGPR ->
// ds_write), compiler-managed waitcnt, NO barriers / NO inline asm in loop.
// 2304 blocks x 4 waves; wave privately owns 16 rows (no cross-wave LDS
// sharing of W). 8 chunks of 64 floats; loads issued 2 chunks ahead into
// alternating named regsets (static indices); ds_write after compute (T14).
// Per load instr: 4 x 256 B contiguous segments. LDS 64 KB -> 2 blk/CU.
// ---------------------------------------------------------------------------
__global__ __launch_bounds__(256) void head_kernel(
    const float* __restrict__ Wh, const float* __restrict__ z,
    short* __restrict__ wnat)
{
    __shared__ __align__(16) char Zl[32 * 1024];      // z bf16 swizzled, 32 KB
    __shared__ __align__(16) char Wl[4][2][4096];     // wave-private dbuf tiles
    const int tid  = threadIdx.x;
    const int lane = tid & 63;
    const int wv   = tid >> 6;

    // stage z once: thread t -> b = t>>3, k-range (t&7)*64..+63, swz ^((b&7)<<4)
    {
        const int b = tid >> 3, ks = (tid & 7) * 64;
        const float* zp = z + (size_t)b * ZD + ks;
        const int bx = (b & 7) << 4;
        #pragma unroll
        for (int j8 = 0; j8 < 8; ++j8) {
            f32x4 v0 = *(const f32x4*)(zp + j8 * 8);
            f32x4 v1 = *(const f32x4*)(zp + j8 * 8 + 4);
            bf16x8 pk;
            pk[0] = f2bf_hw(v0.x); pk[1] = f2bf_hw(v0.y);
            pk[2] = f2bf_hw(v0.z); pk[3] = f2bf_hw(v0.w);
            pk[4] = f2bf_hw(v1.x); pk[5] = f2bf_hw(v1.y);
            pk[6] = f2bf_hw(v1.z); pk[7] = f2bf_hw(v1.w);
            *(bf16x8*)(Zl + b * 1024 + ((ks * 2 + j8 * 16) ^ bx)) = pk;
        }
    }
    __syncthreads();   // Zl ready (only barrier in the kernel)

    const int rl = lane & 15;            // W-row within wave tile (D col); b in A
    const int kq = lane >> 4;            // k-quadrant / row sub-index for loads
    const int zxor = (rl & 7) << 4;
    const int row0 = blockIdx.x * 64 + wv * 16;

    // load: instr j covers rows {j*4+kq}, lane&15 gives 16B granule in 256B chunk
    const float* lsrc = Wh + (size_t)(row0 + kq) * ZD + (lane & 15) * 4;
    char* WT = (char*)Wl[wv][0];         // [0]:4096 bytes, [1] at +4096

    #define LOADC(c, R)                                                         \
        _Pragma("unroll")                                                       \
        for (int j = 0; j < 4; ++j)                                             \
            R[j] = *(const f32x4*)(lsrc + (size_t)(j * 4) * ZD + (c) * 64);

    // ds_write: row = j*4+kq, granule (lane&15) XOR (row&7)
    #define WRC(buf, R)                                                         \
        _Pragma("unroll")                                                       \
        for (int j = 0; j < 4; ++j) {                                           \
            const int row_ = j * 4 + kq;                                        \
            *(f32x4*)(WT + (buf) * 4096 + row_ * 256 +                          \
                      (((lane & 15) * 16) ^ ((row_ & 7) << 4))) = R[j];         \
        }

    f32x4 RA[4], RB[4];
    LOADC(0, RA);
    LOADC(1, RB);
    WRC(0, RA);

    f32x4 acc0 = {0.f, 0.f, 0.f, 0.f}, acc1 = {0.f, 0.f, 0.f, 0.f};

    #pragma unroll
    for (int c = 0; c < 8; ++c) {
        if (c + 2 < 8) {
            if ((c & 1) == 0) { LOADC(c + 2, RA); }
            else              { LOADC(c + 2, RB); }
        }
        // compute chunk c from buf c&1
        #pragma unroll
        for (int ks = 0; ks < 2; ++ks) {
            const int koff = (c * 128 + ks * 64 + kq * 16) ^ zxor;
            bf16x8 a0 = *(const bf16x8*)(Zl + rl * 1024 + koff);
            bf16x8 a1 = *(const bf16x8*)(Zl + (16 + rl) * 1024 + koff);
            const char* wb = WT + (c & 1) * 4096 + rl * 256;
            f32x4 lo = *(const f32x4*)(wb + ((ks * 128 + kq * 32) ^ zxor));
            f32x4 hi = *(const f32x4*)(wb + ((ks * 128 + kq * 32 + 16) ^ zxor));
            bf16x8 bw;
            bw[0] = f2bf_hw(lo.x); bw[1] = f2bf_hw(lo.y);
            bw[2] = f2bf_hw(lo.z); bw[3] = f2bf_hw(lo.w);
            bw[4] = f2bf_hw(hi.x); bw[5] = f2bf_hw(hi.y);
            bw[6] = f2bf_hw(hi.z); bw[7] = f2bf_hw(hi.w);
            acc0 = __builtin_amdgcn_mfma_f32_16x16x32_bf16(a0, bw, acc0, 0, 0, 0);
            acc1 = __builtin_amdgcn_mfma_f32_16x16x32_bf16(a1, bw, acc1, 0, 0, 0);
        }
        // write chunk c+1 (loads issued 2 iters ago -> arrived; T14 write-late)
        if (c + 1 < 8) {
            if ((c & 1) == 0) { WRC(1, RB); }
            else              { WRC(0, RA); }
        }
    }
    #undef LOADC
    #undef WRC

    // D: col = lane&15 (= W row), row = 4*kq+reg (= batch b). Natural layout.
    const int rowg = row0 + rl;
    #pragma unroll
    for (int reg = 0; reg < 4; ++reg) {
        const int b0 = kq * 4 + reg;
        wnat[(size_t)b0 * WROWS + rowg]        = f2bf(acc0[reg]);
        wnat[(size_t)(16 + b0) * WROWS + rowg] = f2bf(acc1[reg]);
    }
}

// ---------------------------------------------------------------------------
// Kernel 1b: repack wnat[b][rowg] -> wbf[b][rs][oi], adding bias.
// ---------------------------------------------------------------------------
__global__ __launch_bounds__(256) void repack_kernel(
    const short* __restrict__ wnat, const float* __restrict__ bh,
    short* __restrict__ wbf)
{
    const int b = blockIdx.y;
    const int oi0 = blockIdx.x * 2048 + threadIdx.x * 8;
    const short* src = wnat + (size_t)b * WROWS + (size_t)oi0 * 9;
    const float* bp  = bh + (size_t)oi0 * 9;

    bf16x8 in[9];
    #pragma unroll
    for (int j = 0; j < 9; ++j) in[j] = *(const bf16x8*)(src + j * 8);
    f32x4 bv[18];
    #pragma unroll
    for (int m = 0; m < 18; ++m) bv[m] = *(const f32x4*)(bp + m * 4);

    #pragma unroll
    for (int rs = 0; rs < 9; ++rs) {
        bf16x8 o;
        #pragma unroll
        for (int jj = 0; jj < 8; ++jj) {
            const int e = jj * 9 + rs;
            float v = bf2f(in[e >> 3][e & 7]) + bv[e >> 2][e & 3];
            o[jj] = f2bf(v);
        }
        *(bf16x8*)(wbf + ((size_t)(b * 9 + rs)) * OI + oi0) = o;
    }
}

// ---------------------------------------------------------------------------
// Kernel 2: x [b][i][h][w] fp32  ->  xt [b][h][w][i] bf16
// ---------------------------------------------------------------------------
__global__ __launch_bounds__(256) void transpose_kernel(
    const float* __restrict__ x, short* __restrict__ xt)
{
    const int h = blockIdx.x;          // 56
    const int b = blockIdx.y;          // 32
    const int w = threadIdx.x & 63;
    const int yq = threadIdx.x >> 6;   // 0..3
    if (w >= WW) return;
    const float* xp = x + (size_t)b * IC * HH * WW + h * WW + w;
    short* op = xt + (((size_t)(b * HH + h)) * WW + w) * IC;
    #pragma unroll
    for (int q = 0; q < 4; ++q) {
        int ic = yq * 4 + q;           // 0..15
        bf16x8 pk;
        #pragma unroll
        for (int j = 0; j < 8; ++j) {
            float v = xp[(size_t)(ic * 8 + j) * (HH * WW)];
            pk[j] = f2bf(v);
        }
        *(bf16x8*)(op + ic * 8) = pk;
    }
}

// ---------------------------------------------------------------------------
// Kernel 3: per-sample conv as 9 shifted GEMMs with bf16 MFMA (unchanged).
// ---------------------------------------------------------------------------
__global__ __launch_bounds__(256) void conv_kernel(
    const short* __restrict__ wbf,   // [b][rs][o][i] bf16
    const short* __restrict__ xt,    // [b][h][w][i]  bf16
    float* __restrict__ out)         // [b][o][h][w]  fp32
{
    __shared__ __align__(16) char Xl[3 * WDIM * 256];  // 44544 B
    __shared__ __align__(16) char Wl[128 * 256];       // 32768 B
    const int tid  = threadIdx.x;
    const int lane = tid & 63;
    const int wv   = tid >> 6;       // wave 0..3
    const int h = blockIdx.x;        // 56
    const int b = blockIdx.y;        // 32

    #pragma unroll
    for (int q = 0; q < 11; ++q) {
        int idx = tid + q * 256;
        if (idx < 3 * WDIM * 16) ((f32x4*)Xl)[idx] = (f32x4){0.f, 0.f, 0.f, 0.f};
    }
    __syncthreads();

    for (int r = 0; r < 3; ++r) {
        int hin = h + r - 1;
        if (hin < 0 || hin >= HH) continue;
        const char* src = (const char*)(xt + ((size_t)(b * HH + hin)) * WW * IC);
        char* dstbase = Xl + (r * WDIM + 1) * 256;
        for (int it = wv; it < 14; it += 4) {
            int c = it * 64 + lane;
            int u = r * WDIM + 1 + (c >> 4);
            int soff = (c * 16) ^ ((u & 7) << 4);
            gll16(src + soff, dstbase + it * 1024);
        }
    }

    f32x4 acc[2][4];
    #pragma unroll
    for (int a = 0; a < 2; ++a)
        #pragma unroll
        for (int p = 0; p < 4; ++p) acc[a][p] = (f32x4){0.f, 0.f, 0.f, 0.f};

    const int axor = (lane & 7) << 4;
    int kkoff[4];
    #pragma unroll
    for (int kk = 0; kk < 4; ++kk) kkoff[kk] = kk * 64 + ((lane >> 4) << 4);

    for (int rs = 0; rs < 9; ++rs) {
        __syncthreads();
        const char* wsrc = (const char*)(wbf + ((size_t)b * NRS + rs) * OI);
        for (int it = wv; it < 32; it += 4) {
            int c = it * 64 + lane;
            int soff = (c * 16) ^ (((c >> 4) & 7) << 4);
            gll16(wsrc + soff, Wl + it * 1024);
        }
        __syncthreads();

        const int r = rs / 3, s = rs - 3 * (rs / 3);
        int ubase[4], bswz[4];
        #pragma unroll
        for (int pf = 0; pf < 4; ++pf) {
            int p = pf * 16 + (lane & 15);
            int pc = p > 55 ? 55 : p;
            int uu = r * WDIM + pc + s;
            ubase[pf] = uu * 256;
            bswz[pf] = (uu & 7) << 4;
        }
        #pragma unroll
        for (int kk = 0; kk < 4; ++kk) {
            bf16x8 a0 = *(const bf16x8*)(Wl + (wv * 32 + (lane & 15)) * 256 +
                                         (kkoff[kk] ^ axor));
            bf16x8 a1 = *(const bf16x8*)(Wl + (wv * 32 + 16 + (lane & 15)) * 256 +
                                         (kkoff[kk] ^ axor));
            #pragma unroll
            for (int pf = 0; pf < 4; ++pf) {
                bf16x8 bv = *(const bf16x8*)(Xl + ubase[pf] + (kkoff[kk] ^ bswz[pf]));
                acc[0][pf] = __builtin_amdgcn_mfma_f32_16x16x32_bf16(a0, bv, acc[0][pf], 0, 0, 0);
                acc[1][pf] = __builtin_amdgcn_mfma_f32_16x16x32_bf16(a1, bv, acc[1][pf], 0, 0, 0);
            }
        }
    }

    const int pcol = lane & 15;
    const int rowq = lane >> 4;
    #pragma unroll
    for (int a = 0; a < 2; ++a) {
        int o0 = wv * 32 + a * 16 + rowq * 4;
        #pragma unroll
        for (int pf = 0; pf < 4; ++pf) {
            int p = pf * 16 + pcol;
            if (p < WW) {
                #pragma unroll
                for (int reg = 0; reg < 4; ++reg) {
                    out[(((size_t)b * OC + (o0 + reg)) * HH + h) * WW + p] = acc[a][pf][reg];
                }
            }
        }
    }
}

extern "C" void kernel_launch(void* const* d_in, const int* in_sizes, int n_in,
                              void* d_out, int out_size, void* d_ws, size_t ws_size,
                              hipStream_t stream) {
    const float* x  = (const float*)d_in[0];   // [32,128,56,56]
    const float* z  = (const float*)d_in[1];   // [32,512]
    const float* Wh = (const float*)d_in[2];   // [147456,512]
    const float* bh = (const float*)d_in[3];   // [147456]
    float* out = (float*)d_out;

    short* wnat = (short*)d_ws;                                  // 9,437,184 B
    short* wbf  = (short*)((char*)d_ws + 9437184);               // 9,437,184 B
    short* xt   = (short*)((char*)d_ws + 18874368);              // 25,690,112 B

    head_kernel<<<dim3(WROWS / 64), 256, 0, stream>>>(Wh, z, wnat);
    repack_kernel<<<dim3(8, 32), 256, 0, stream>>>(wnat, bh, wbf);
    transpose_kernel<<<dim3(HH, BB), 256, 0, stream>>>(x, xt);
    conv_kernel<<<dim3(HH, BB), 256, 0, stream>>>(wbf, xt, out);
}

// Round 7
// 164.071 us; speedup vs baseline: 1.0292x; 1.0292x over previous
//
#include <hip/hip_runtime.h>
#include <hip/hip_bf16.h>
#include <stdint.h>

#define BB 32
#define IC 128
#define OC 128
#define HH 56
#define WW 56
#define ZD 512
#define NRS 9
#define OI (OC*IC)            // 16384
#define WROWS (OI*NRS)        // 147456
#define WDIM 58               // conv LDS width index u = w_in+1, 0..57
#define NHEADBLK (WROWS / 64) // 2304
#define NTRBLK (HH * BB)      // 1792

typedef float  f32x4  __attribute__((ext_vector_type(4)));
typedef short  bf16x8 __attribute__((ext_vector_type(8)));

static __device__ __forceinline__ short f2bf(float f) {
    uint32_t u = __float_as_uint(f);
    uint32_t r = (u + 0x7fffu + ((u >> 16) & 1u)) >> 16;
    return (short)r;
}
static __device__ __forceinline__ short f2bf_hw(float f) {
    __hip_bfloat16 h = __float2bfloat16(f);
    return *reinterpret_cast<short*>(&h);
}
static __device__ __forceinline__ float bf2f(short s) {
    uint32_t u = ((uint32_t)(uint16_t)s) << 16;
    return __uint_as_float(u);
}
static __device__ __forceinline__ void gll16(const void* g, void* l) {
    __builtin_amdgcn_global_load_lds(
        (const __attribute__((address_space(1))) uint32_t*)g,
        (__attribute__((address_space(3))) uint32_t*)l, 16, 0, 0);
}

// ---------------------------------------------------------------------------
// Kernel 1 (v7): FUSED head + transpose, one dispatch for concurrency.
// Head blocks (0..2303): direct-to-fragment max-ILP streaming. Each wave owns
// 16 Wh rows; issues its ENTIRE 16 KB read (32 x dwordx4 into 128 VGPRs,
// in order) before the first consume -> 128 KB/CU standing in flight.
// No LDS for W, no barriers after z-stage. Consume order = issue order, so
// the compiler emits counted vmcnt drains (no vmcnt(0) until the last frag).
// Transpose blocks (2304..4095): x NCHW fp32 -> xt [b][h][w][i] bf16.
// ---------------------------------------------------------------------------
__global__ __launch_bounds__(256, 2) void fused_head_tr_kernel(
    const float* __restrict__ Wh, const float* __restrict__ z,
    short* __restrict__ wnat,
    const float* __restrict__ x, short* __restrict__ xt)
{
    if (blockIdx.x >= NHEADBLK) {
        // ---------------- transpose part ----------------
        const int bx = blockIdx.x - NHEADBLK;
        const int b = bx / HH;
        const int h = bx - b * HH;
        const int w = threadIdx.x & 63;
        const int yq = threadIdx.x >> 6;
        if (w >= WW) return;
        const float* xp = x + (size_t)b * IC * HH * WW + h * WW + w;
        short* op = xt + (((size_t)(b * HH + h)) * WW + w) * IC;
        #pragma unroll
        for (int q = 0; q < 4; ++q) {
            int ic = yq * 4 + q;
            bf16x8 pk;
            #pragma unroll
            for (int j = 0; j < 8; ++j) {
                float v = xp[(size_t)(ic * 8 + j) * (HH * WW)];
                pk[j] = f2bf(v);
            }
            *(bf16x8*)(op + ic * 8) = pk;
        }
        return;
    }

    // ---------------- head part ----------------
    __shared__ __align__(16) char Zl[32 * 1024];   // z bf16 swizzled, 32 KB
    const int tid  = threadIdx.x;
    const int lane = tid & 63;
    const int wv   = tid >> 6;

    // stage z once: thread t -> b = t>>3, k-range (t&7)*64..+63, swz ^((b&7)<<4)
    {
        const int b = tid >> 3, ks = (tid & 7) * 64;
        const float* zp = z + (size_t)b * ZD + ks;
        const int bx = (b & 7) << 4;
        #pragma unroll
        for (int j8 = 0; j8 < 8; ++j8) {
            f32x4 v0 = *(const f32x4*)(zp + j8 * 8);
            f32x4 v1 = *(const f32x4*)(zp + j8 * 8 + 4);
            bf16x8 pk;
            pk[0] = f2bf_hw(v0.x); pk[1] = f2bf_hw(v0.y);
            pk[2] = f2bf_hw(v0.z); pk[3] = f2bf_hw(v0.w);
            pk[4] = f2bf_hw(v1.x); pk[5] = f2bf_hw(v1.y);
            pk[6] = f2bf_hw(v1.z); pk[7] = f2bf_hw(v1.w);
            *(bf16x8*)(Zl + b * 1024 + ((ks * 2 + j8 * 16) ^ bx)) = pk;
        }
    }
    __syncthreads();   // Zl ready (only barrier)

    const int rl = lane & 15;            // Wh row within wave tile (D col); b in A
    const int kq = lane >> 4;            // k-quadrant
    const int zxor = (rl & 7) << 4;
    const int rowg = blockIdx.x * 64 + wv * 16 + rl;

    // B-frag source: lane holds Wh[rowg][kb*32 + kq*8 .. +7] (32 B = 2 dwordx4)
    const char* wp = (const char*)Wh + (size_t)rowg * (ZD * 4) + kq * 32;

    // issue the ENTIRE 16 KB wave read up front, in consumption order
    f32x4 wd[32];
    #pragma unroll
    for (int i = 0; i < 16; ++i) {
        wd[2 * i]     = *(const f32x4*)(wp + i * 128);
        wd[2 * i + 1] = *(const f32x4*)(wp + i * 128 + 16);
    }

    f32x4 acc0 = {0.f, 0.f, 0.f, 0.f}, acc1 = {0.f, 0.f, 0.f, 0.f};
    #pragma unroll
    for (int kb = 0; kb < 16; ++kb) {
        const int koff = (kb * 64 + kq * 16) ^ zxor;
        bf16x8 a0 = *(const bf16x8*)(Zl + rl * 1024 + koff);
        bf16x8 a1 = *(const bf16x8*)(Zl + (16 + rl) * 1024 + koff);
        f32x4 lo = wd[2 * kb];
        f32x4 hi = wd[2 * kb + 1];
        bf16x8 bw;
        bw[0] = f2bf_hw(lo.x); bw[1] = f2bf_hw(lo.y);
        bw[2] = f2bf_hw(lo.z); bw[3] = f2bf_hw(lo.w);
        bw[4] = f2bf_hw(hi.x); bw[5] = f2bf_hw(hi.y);
        bw[6] = f2bf_hw(hi.z); bw[7] = f2bf_hw(hi.w);
        acc0 = __builtin_amdgcn_mfma_f32_16x16x32_bf16(a0, bw, acc0, 0, 0, 0);
        acc1 = __builtin_amdgcn_mfma_f32_16x16x32_bf16(a1, bw, acc1, 0, 0, 0);
    }

    // D: col = lane&15 (= W row), row = 4*kq+reg (= batch b). Natural layout.
    #pragma unroll
    for (int reg = 0; reg < 4; ++reg) {
        const int b0 = kq * 4 + reg;
        wnat[(size_t)b0 * WROWS + rowg]        = f2bf(acc0[reg]);
        wnat[(size_t)(16 + b0) * WROWS + rowg] = f2bf(acc1[reg]);
    }
}

// ---------------------------------------------------------------------------
// Kernel 1b: repack wnat[b][rowg] -> wbf[b][rs][oi], adding bias.
// ---------------------------------------------------------------------------
__global__ __launch_bounds__(256) void repack_kernel(
    const short* __restrict__ wnat, const float* __restrict__ bh,
    short* __restrict__ wbf)
{
    const int b = blockIdx.y;
    const int oi0 = blockIdx.x * 2048 + threadIdx.x * 8;
    const short* src = wnat + (size_t)b * WROWS + (size_t)oi0 * 9;
    const float* bp  = bh + (size_t)oi0 * 9;

    bf16x8 in[9];
    #pragma unroll
    for (int j = 0; j < 9; ++j) in[j] = *(const bf16x8*)(src + j * 8);
    f32x4 bv[18];
    #pragma unroll
    for (int m = 0; m < 18; ++m) bv[m] = *(const f32x4*)(bp + m * 4);

    #pragma unroll
    for (int rs = 0; rs < 9; ++rs) {
        bf16x8 o;
        #pragma unroll
        for (int jj = 0; jj < 8; ++jj) {
            const int e = jj * 9 + rs;
            float v = bf2f(in[e >> 3][e & 7]) + bv[e >> 2][e & 3];
            o[jj] = f2bf(v);
        }
        *(bf16x8*)(wbf + ((size_t)(b * 9 + rs)) * OI + oi0) = o;
    }
}

// ---------------------------------------------------------------------------
// Kernel 3: per-sample conv as 9 shifted GEMMs with bf16 MFMA (unchanged).
// ---------------------------------------------------------------------------
__global__ __launch_bounds__(256) void conv_kernel(
    const short* __restrict__ wbf,   // [b][rs][o][i] bf16
    const short* __restrict__ xt,    // [b][h][w][i]  bf16
    float* __restrict__ out)         // [b][o][h][w]  fp32
{
    __shared__ __align__(16) char Xl[3 * WDIM * 256];  // 44544 B
    __shared__ __align__(16) char Wl[128 * 256];       // 32768 B
    const int tid  = threadIdx.x;
    const int lane = tid & 63;
    const int wv   = tid >> 6;       // wave 0..3
    const int h = blockIdx.x;        // 56
    const int b = blockIdx.y;        // 32

    #pragma unroll
    for (int q = 0; q < 11; ++q) {
        int idx = tid + q * 256;
        if (idx < 3 * WDIM * 16) ((f32x4*)Xl)[idx] = (f32x4){0.f, 0.f, 0.f, 0.f};
    }
    __syncthreads();

    for (int r = 0; r < 3; ++r) {
        int hin = h + r - 1;
        if (hin < 0 || hin >= HH) continue;
        const char* src = (const char*)(xt + ((size_t)(b * HH + hin)) * WW * IC);
        char* dstbase = Xl + (r * WDIM + 1) * 256;
        for (int it = wv; it < 14; it += 4) {
            int c = it * 64 + lane;
            int u = r * WDIM + 1 + (c >> 4);
            int soff = (c * 16) ^ ((u & 7) << 4);
            gll16(src + soff, dstbase + it * 1024);
        }
    }

    f32x4 acc[2][4];
    #pragma unroll
    for (int a = 0; a < 2; ++a)
        #pragma unroll
        for (int p = 0; p < 4; ++p) acc[a][p] = (f32x4){0.f, 0.f, 0.f, 0.f};

    const int axor = (lane & 7) << 4;
    int kkoff[4];
    #pragma unroll
    for (int kk = 0; kk < 4; ++kk) kkoff[kk] = kk * 64 + ((lane >> 4) << 4);

    for (int rs = 0; rs < 9; ++rs) {
        __syncthreads();
        const char* wsrc = (const char*)(wbf + ((size_t)b * NRS + rs) * OI);
        for (int it = wv; it < 32; it += 4) {
            int c = it * 64 + lane;
            int soff = (c * 16) ^ (((c >> 4) & 7) << 4);
            gll16(wsrc + soff, Wl + it * 1024);
        }
        __syncthreads();

        const int r = rs / 3, s = rs - 3 * (rs / 3);
        int ubase[4], bswz[4];
        #pragma unroll
        for (int pf = 0; pf < 4; ++pf) {
            int p = pf * 16 + (lane & 15);
            int pc = p > 55 ? 55 : p;
            int uu = r * WDIM + pc + s;
            ubase[pf] = uu * 256;
            bswz[pf] = (uu & 7) << 4;
        }
        #pragma unroll
        for (int kk = 0; kk < 4; ++kk) {
            bf16x8 a0 = *(const bf16x8*)(Wl + (wv * 32 + (lane & 15)) * 256 +
                                         (kkoff[kk] ^ axor));
            bf16x8 a1 = *(const bf16x8*)(Wl + (wv * 32 + 16 + (lane & 15)) * 256 +
                                         (kkoff[kk] ^ axor));
            #pragma unroll
            for (int pf = 0; pf < 4; ++pf) {
                bf16x8 bv = *(const bf16x8*)(Xl + ubase[pf] + (kkoff[kk] ^ bswz[pf]));
                acc[0][pf] = __builtin_amdgcn_mfma_f32_16x16x32_bf16(a0, bv, acc[0][pf], 0, 0, 0);
                acc[1][pf] = __builtin_amdgcn_mfma_f32_16x16x32_bf16(a1, bv, acc[1][pf], 0, 0, 0);
            }
        }
    }

    const int pcol = lane & 15;
    const int rowq = lane >> 4;
    #pragma unroll
    for (int a = 0; a < 2; ++a) {
        int o0 = wv * 32 + a * 16 + rowq * 4;
        #pragma unroll
        for (int pf = 0; pf < 4; ++pf) {
            int p = pf * 16 + pcol;
            if (p < WW) {
                #pragma unroll
                for (int reg = 0; reg < 4; ++reg) {
                    out[(((size_t)b * OC + (o0 + reg)) * HH + h) * WW + p] = acc[a][pf][reg];
                }
            }
        }
    }
}

extern "C" void kernel_launch(void* const* d_in, const int* in_sizes, int n_in,
                              void* d_out, int out_size, void* d_ws, size_t ws_size,
                              hipStream_t stream) {
    const float* x  = (const float*)d_in[0];   // [32,128,56,56]
    const float* z  = (const float*)d_in[1];   // [32,512]
    const float* Wh = (const float*)d_in[2];   // [147456,512]
    const float* bh = (const float*)d_in[3];   // [147456]
    float* out = (float*)d_out;

    short* wnat = (short*)d_ws;                                  // 9,437,184 B
    short* wbf  = (short*)((char*)d_ws + 9437184);               // 9,437,184 B
    short* xt   = (short*)((char*)d_ws + 18874368);              // 25,690,112 B

    fused_head_tr_kernel<<<dim3(NHEADBLK + NTRBLK), 256, 0, stream>>>(Wh, z, wnat, x, xt);
    repack_kernel<<<dim3(8, 32), 256, 0, stream>>>(wnat, bh, wbf);
    transpose_kernel_dummy:;
    conv_kernel<<<dim3(HH, BB), 256, 0, stream>>>(wbf, xt, out);
}

// Round 8
// 158.125 us; speedup vs baseline: 1.0679x; 1.0376x over previous
//
#include <hip/hip_runtime.h>
#include <hip/hip_bf16.h>
#include <stdint.h>

#define BB 32
#define IC 128
#define OC 128
#define HH 56
#define WW 56
#define ZD 512
#define NRS 9
#define OI (OC*IC)            // 16384
#define WROWS (OI*NRS)        // 147456
#define WDIM 58               // conv LDS width index u = w_in+1, 0..57
#define NHEADBLK (WROWS / 64) // 2304
#define NTRBLK (HH * BB)      // 1792
#define XTILE (4 * WDIM * 256)  // 59392 B

typedef float  f32x4  __attribute__((ext_vector_type(4)));
typedef short  bf16x8 __attribute__((ext_vector_type(8)));

static __device__ __forceinline__ short f2bf(float f) {
    uint32_t u = __float_as_uint(f);
    uint32_t r = (u + 0x7fffu + ((u >> 16) & 1u)) >> 16;
    return (short)r;
}
static __device__ __forceinline__ short f2bf_hw(float f) {
    __hip_bfloat16 h = __float2bfloat16(f);
    return *reinterpret_cast<short*>(&h);
}
static __device__ __forceinline__ float bf2f(short s) {
    uint32_t u = ((uint32_t)(uint16_t)s) << 16;
    return __uint_as_float(u);
}
static __device__ __forceinline__ void gll16(const void* g, void* l) {
    __builtin_amdgcn_global_load_lds(
        (const __attribute__((address_space(1))) uint32_t*)g,
        (__attribute__((address_space(3))) uint32_t*)l, 16, 0, 0);
}

// ---------------------------------------------------------------------------
// Kernel 1 (v7): FUSED head + transpose (unchanged from round 7 — head is at
// the ~3 TB/s pure-read roofline; six structural variants all pinned here).
// ---------------------------------------------------------------------------
__global__ __launch_bounds__(256, 2) void fused_head_tr_kernel(
    const float* __restrict__ Wh, const float* __restrict__ z,
    short* __restrict__ wnat,
    const float* __restrict__ x, short* __restrict__ xt)
{
    if (blockIdx.x >= NHEADBLK) {
        // ---------------- transpose part ----------------
        const int bx = blockIdx.x - NHEADBLK;
        const int b = bx / HH;
        const int h = bx - b * HH;
        const int w = threadIdx.x & 63;
        const int yq = threadIdx.x >> 6;
        if (w >= WW) return;
        const float* xp = x + (size_t)b * IC * HH * WW + h * WW + w;
        short* op = xt + (((size_t)(b * HH + h)) * WW + w) * IC;
        #pragma unroll
        for (int q = 0; q < 4; ++q) {
            int ic = yq * 4 + q;
            bf16x8 pk;
            #pragma unroll
            for (int j = 0; j < 8; ++j) {
                float v = xp[(size_t)(ic * 8 + j) * (HH * WW)];
                pk[j] = f2bf(v);
            }
            *(bf16x8*)(op + ic * 8) = pk;
        }
        return;
    }

    // ---------------- head part ----------------
    __shared__ __align__(16) char Zl[32 * 1024];   // z bf16 swizzled, 32 KB
    const int tid  = threadIdx.x;
    const int lane = tid & 63;
    const int wv   = tid >> 6;

    {
        const int b = tid >> 3, ks = (tid & 7) * 64;
        const float* zp = z + (size_t)b * ZD + ks;
        const int bx = (b & 7) << 4;
        #pragma unroll
        for (int j8 = 0; j8 < 8; ++j8) {
            f32x4 v0 = *(const f32x4*)(zp + j8 * 8);
            f32x4 v1 = *(const f32x4*)(zp + j8 * 8 + 4);
            bf16x8 pk;
            pk[0] = f2bf_hw(v0.x); pk[1] = f2bf_hw(v0.y);
            pk[2] = f2bf_hw(v0.z); pk[3] = f2bf_hw(v0.w);
            pk[4] = f2bf_hw(v1.x); pk[5] = f2bf_hw(v1.y);
            pk[6] = f2bf_hw(v1.z); pk[7] = f2bf_hw(v1.w);
            *(bf16x8*)(Zl + b * 1024 + ((ks * 2 + j8 * 16) ^ bx)) = pk;
        }
    }
    __syncthreads();   // Zl ready (only barrier)

    const int rl = lane & 15;
    const int kq = lane >> 4;
    const int zxor = (rl & 7) << 4;
    const int rowg = blockIdx.x * 64 + wv * 16 + rl;

    const char* wp = (const char*)Wh + (size_t)rowg * (ZD * 4) + kq * 32;

    f32x4 wd[32];
    #pragma unroll
    for (int i = 0; i < 16; ++i) {
        wd[2 * i]     = *(const f32x4*)(wp + i * 128);
        wd[2 * i + 1] = *(const f32x4*)(wp + i * 128 + 16);
    }

    f32x4 acc0 = {0.f, 0.f, 0.f, 0.f}, acc1 = {0.f, 0.f, 0.f, 0.f};
    #pragma unroll
    for (int kb = 0; kb < 16; ++kb) {
        const int koff = (kb * 64 + kq * 16) ^ zxor;
        bf16x8 a0 = *(const bf16x8*)(Zl + rl * 1024 + koff);
        bf16x8 a1 = *(const bf16x8*)(Zl + (16 + rl) * 1024 + koff);
        f32x4 lo = wd[2 * kb];
        f32x4 hi = wd[2 * kb + 1];
        bf16x8 bw;
        bw[0] = f2bf_hw(lo.x); bw[1] = f2bf_hw(lo.y);
        bw[2] = f2bf_hw(lo.z); bw[3] = f2bf_hw(lo.w);
        bw[4] = f2bf_hw(hi.x); bw[5] = f2bf_hw(hi.y);
        bw[6] = f2bf_hw(hi.z); bw[7] = f2bf_hw(hi.w);
        acc0 = __builtin_amdgcn_mfma_f32_16x16x32_bf16(a0, bw, acc0, 0, 0, 0);
        acc1 = __builtin_amdgcn_mfma_f32_16x16x32_bf16(a1, bw, acc1, 0, 0, 0);
    }

    #pragma unroll
    for (int reg = 0; reg < 4; ++reg) {
        const int b0 = kq * 4 + reg;
        wnat[(size_t)b0 * WROWS + rowg]        = f2bf(acc0[reg]);
        wnat[(size_t)(16 + b0) * WROWS + rowg] = f2bf(acc1[reg]);
    }
}

// ---------------------------------------------------------------------------
// Kernel 1b: repack wnat[b][rowg] -> wbf[b][rs][oi], adding bias (unchanged).
// ---------------------------------------------------------------------------
__global__ __launch_bounds__(256) void repack_kernel(
    const short* __restrict__ wnat, const float* __restrict__ bh,
    short* __restrict__ wbf)
{
    const int b = blockIdx.y;
    const int oi0 = blockIdx.x * 2048 + threadIdx.x * 8;
    const short* src = wnat + (size_t)b * WROWS + (size_t)oi0 * 9;
    const float* bp  = bh + (size_t)oi0 * 9;

    bf16x8 in[9];
    #pragma unroll
    for (int j = 0; j < 9; ++j) in[j] = *(const bf16x8*)(src + j * 8);
    f32x4 bv[18];
    #pragma unroll
    for (int m = 0; m < 18; ++m) bv[m] = *(const f32x4*)(bp + m * 4);

    #pragma unroll
    for (int rs = 0; rs < 9; ++rs) {
        bf16x8 o;
        #pragma unroll
        for (int jj = 0; jj < 8; ++jj) {
            const int e = jj * 9 + rs;
            float v = bf2f(in[e >> 3][e & 7]) + bv[e >> 2][e & 3];
            o[jj] = f2bf(v);
        }
        *(bf16x8*)(wbf + ((size_t)(b * 9 + rs)) * OI + oi0) = o;
    }
}

// ---------------------------------------------------------------------------
// Kernel 3 (v2): conv, BH=2 output rows per block, 512 thr = 8 waves
// (wave = (hh, o-quarter)).  W[rs] slices triple-buffered (reuse distance 2),
// ONE barrier + counted vmcnt(4) per rs (no drain in the loop).  X tile
// [4][58][128] bf16 staged once in prologue.  LDS 154 KB -> 1 block/CU.
// Per-wave-uniform newest-4 loads = next W slice, so vmcnt(4) before the
// barrier guarantees W[rs] (and, transitively, X/W0) landed for all waves.
// ---------------------------------------------------------------------------
__global__ __launch_bounds__(512) void conv_kernel(
    const short* __restrict__ wbf,   // [b][rs][o][i] bf16
    const short* __restrict__ xt,    // [b][h][w][i]  bf16
    float* __restrict__ out)         // [b][o][h][w]  fp32
{
    __shared__ __align__(16) char Xl[XTILE];       // 59392 B
    __shared__ __align__(16) char Wl[3][32768];    // 98304 B
    const int tid  = threadIdx.x;
    const int lane = tid & 63;
    const int wv   = tid >> 6;       // 0..7
    const int og   = wv & 3;         // o-quarter
    const int hh   = wv >> 2;        // output row within block
    const int h0 = blockIdx.x * 2;
    const int b  = blockIdx.y;

    // zero X tile (halo + missing border rows)
    #pragma unroll
    for (int q = 0; q < 8; ++q) {
        int idx = tid + q * 512;
        if (idx < XTILE / 16) ((f32x4*)Xl)[idx] = (f32x4){0.f, 0.f, 0.f, 0.f};
    }
    __syncthreads();

    // stage X rows 0..3 (input hin = h0 + r - 1), pre-swizzled source
    for (int r = 0; r < 4; ++r) {
        int hin = h0 + r - 1;
        if (hin < 0 || hin >= HH) continue;
        const char* src = (const char*)(xt + ((size_t)(b * HH + hin)) * WW * IC);
        char* dstb = Xl + (r * WDIM + 1) * 256;
        for (int it = wv; it < 14; it += 8) {
            int c = it * 64 + lane;
            int u = r * WDIM + 1 + (c >> 4);
            int soff = (c * 16) ^ ((u & 7) << 4);
            gll16(src + soff, dstb + it * 1024);
        }
    }

    // W staging: 4 gll16 per wave per slice (uniform across waves)
    #define STAGE_CW(rs_, buf_)                                                 \
        {                                                                       \
            const char* ws_ = (const char*)(wbf +                               \
                ((size_t)b * NRS + (rs_)) * OI);                                \
            _Pragma("unroll")                                                   \
            for (int it_ = 0; it_ < 4; ++it_) {                                 \
                int c_ = (wv * 4 + it_) * 64 + lane;                            \
                int so_ = (c_ * 16) ^ (((c_ >> 4) & 7) << 4);                   \
                gll16(ws_ + so_, Wl[buf_] + (wv * 4 + it_) * 1024);             \
            }                                                                   \
        }

    STAGE_CW(0, 0);

    f32x4 acc[2][4];   // [aa][pf]
    #pragma unroll
    for (int a = 0; a < 2; ++a)
        #pragma unroll
        for (int p = 0; p < 4; ++p) acc[a][p] = (f32x4){0.f, 0.f, 0.f, 0.f};

    const int axor = (lane & 7) << 4;
    int kkoff[4];
    #pragma unroll
    for (int kk = 0; kk < 4; ++kk) kkoff[kk] = kk * 64 + ((lane >> 4) << 4);

    for (int rs = 0; rs < 9; ++rs) {
        if (rs < 8) STAGE_CW(rs + 1, (rs + 1) % 3);
        if (rs == 8) { asm volatile("s_waitcnt vmcnt(0)" ::: "memory"); }
        else         { asm volatile("s_waitcnt vmcnt(4)" ::: "memory"); }
        __builtin_amdgcn_sched_barrier(0);
        __builtin_amdgcn_s_barrier();
        __builtin_amdgcn_sched_barrier(0);

        const char* Wb = Wl[rs % 3];
        const int r = rs / 3, s = rs - 3 * r;
        int ubase[4], bswz[4];
        #pragma unroll
        for (int pf = 0; pf < 4; ++pf) {
            int p = pf * 16 + (lane & 15);
            int pc = p > 55 ? 55 : p;            // clamp garbage lanes
            int uu = (hh + r) * WDIM + pc + s;   // tile row = hh + r
            ubase[pf] = uu * 256;
            bswz[pf] = (uu & 7) << 4;
        }
        #pragma unroll
        for (int kk = 0; kk < 4; ++kk) {
            bf16x8 a0 = *(const bf16x8*)(Wb + (og * 32 + (lane & 15)) * 256 +
                                         (kkoff[kk] ^ axor));
            bf16x8 a1 = *(const bf16x8*)(Wb + (og * 32 + 16 + (lane & 15)) * 256 +
                                         (kkoff[kk] ^ axor));
            #pragma unroll
            for (int pf = 0; pf < 4; ++pf) {
                bf16x8 bv = *(const bf16x8*)(Xl + ubase[pf] + (kkoff[kk] ^ bswz[pf]));
                acc[0][pf] = __builtin_amdgcn_mfma_f32_16x16x32_bf16(a0, bv, acc[0][pf], 0, 0, 0);
                acc[1][pf] = __builtin_amdgcn_mfma_f32_16x16x32_bf16(a1, bv, acc[1][pf], 0, 0, 0);
            }
        }
    }
    #undef STAGE_CW

    // epilogue: D col = lane&15 (=p), row = 4*(lane>>4)+reg (=o offset)
    const int pcol = lane & 15;
    const int rowq = lane >> 4;
    const int hO = h0 + hh;
    #pragma unroll
    for (int aa = 0; aa < 2; ++aa) {
        int o0 = og * 32 + aa * 16 + rowq * 4;
        #pragma unroll
        for (int pf = 0; pf < 4; ++pf) {
            int p = pf * 16 + pcol;
            if (p < WW) {
                #pragma unroll
                for (int reg = 0; reg < 4; ++reg) {
                    out[(((size_t)b * OC + (o0 + reg)) * HH + hO) * WW + p] = acc[aa][pf][reg];
                }
            }
        }
    }
}

extern "C" void kernel_launch(void* const* d_in, const int* in_sizes, int n_in,
                              void* d_out, int out_size, void* d_ws, size_t ws_size,
                              hipStream_t stream) {
    const float* x  = (const float*)d_in[0];   // [32,128,56,56]
    const float* z  = (const float*)d_in[1];   // [32,512]
    const float* Wh = (const float*)d_in[2];   // [147456,512]
    const float* bh = (const float*)d_in[3];   // [147456]
    float* out = (float*)d_out;

    short* wnat = (short*)d_ws;                                  // 9,437,184 B
    short* wbf  = (short*)((char*)d_ws + 9437184);               // 9,437,184 B
    short* xt   = (short*)((char*)d_ws + 18874368);              // 25,690,112 B

    fused_head_tr_kernel<<<dim3(NHEADBLK + NTRBLK), 256, 0, stream>>>(Wh, z, wnat, x, xt);
    repack_kernel<<<dim3(8, 32), 256, 0, stream>>>(wnat, bh, wbf);
    conv_kernel<<<dim3(HH / 2, BB), 512, 0, stream>>>(wbf, xt, out);
}

// Round 9
// 153.796 us; speedup vs baseline: 1.0979x; 1.0281x over previous
//
#include <hip/hip_runtime.h>
#include <hip/hip_bf16.h>
#include <stdint.h>

#define BB 32
#define IC 128
#define OC 128
#define HH 56
#define WW 56
#define ZD 512
#define NRS 9
#define OI (OC*IC)            // 16384
#define WROWS (OI*NRS)        // 147456
#define WDIM 58               // conv LDS width index u = w_in+1, 0..57
#define NHEADBLK 1024         // 144 rows each (16 oi x 9 rs)
#define NTRBLK (HH * BB)      // 1792
#define XTILE (4 * WDIM * 256)  // 59392 B

typedef float  f32x4  __attribute__((ext_vector_type(4)));
typedef short  bf16x8 __attribute__((ext_vector_type(8)));
typedef short  s16x4  __attribute__((ext_vector_type(4)));

static __device__ __forceinline__ short f2bf(float f) {
    uint32_t u = __float_as_uint(f);
    uint32_t r = (u + 0x7fffu + ((u >> 16) & 1u)) >> 16;
    return (short)r;
}
static __device__ __forceinline__ short f2bf_hw(float f) {
    __hip_bfloat16 h = __float2bfloat16(f);
    return *reinterpret_cast<short*>(&h);
}
static __device__ __forceinline__ float bf2f(short s) {
    uint32_t u = ((uint32_t)(uint16_t)s) << 16;
    return __uint_as_float(u);
}
static __device__ __forceinline__ void gll16(const void* g, void* l) {
    __builtin_amdgcn_global_load_lds(
        (const __attribute__((address_space(1))) uint32_t*)g,
        (__attribute__((address_space(3))) uint32_t*)l, 16, 0, 0);
}

// ---------------------------------------------------------------------------
// Kernel 1 (v8): FUSED head + in-block repack + transpose.
// Head blocks (0..1023): 144 rows = 16 oi x 9 rs, 9 waves x 16 rows.
// Per wave: rotating wd[16] in-flight regs (issue 8 kb ahead, static slots),
// MFMA vs z in LDS, results -> Sl[144][32b] (swizzled), then in-block repack
// phase writes wbf[b][rs][oi] directly with bias. No wnat, no repack kernel.
// Transpose blocks (1024..2815): x NCHW fp32 -> xt [b][h][w][i] bf16.
// ---------------------------------------------------------------------------
__global__ __launch_bounds__(576, 1) void fused_head_tr_kernel(
    const float* __restrict__ Wh, const float* __restrict__ z,
    const float* __restrict__ bh, short* __restrict__ wbf,
    const float* __restrict__ x, short* __restrict__ xt)
{
    if (blockIdx.x >= NHEADBLK) {
        // ---------------- transpose part (512 active threads) --------------
        const int bx = blockIdx.x - NHEADBLK;
        const int b = bx / HH;
        const int h = bx - b * HH;
        const int tid = threadIdx.x;
        if (tid >= 512) return;
        const int w = tid & 63;
        const int yq = tid >> 6;           // 0..7
        if (w >= WW) return;
        const float* xp = x + (size_t)b * IC * HH * WW + h * WW + w;
        short* op = xt + (((size_t)(b * HH + h)) * WW + w) * IC;
        #pragma unroll
        for (int q = 0; q < 2; ++q) {
            int ic = yq * 2 + q;           // 0..15
            bf16x8 pk;
            #pragma unroll
            for (int j = 0; j < 8; ++j) {
                float v = xp[(size_t)(ic * 8 + j) * (HH * WW)];
                pk[j] = f2bf(v);
            }
            *(bf16x8*)(op + ic * 8) = pk;
        }
        return;
    }

    // ---------------- head part ----------------
    __shared__ __align__(16) char Zl[32 * 1024];   // z bf16 swizzled, 32 KB
    __shared__ __align__(16) char Sl[144 * 64];    // result staging, 9216 B
    const int tid  = threadIdx.x;
    const int lane = tid & 63;
    const int wv   = tid >> 6;                     // 0..8

    // stage z once (first 256 threads)
    if (tid < 256) {
        const int b = tid >> 3, ks = (tid & 7) * 64;
        const float* zp = z + (size_t)b * ZD + ks;
        const int bx = (b & 7) << 4;
        #pragma unroll
        for (int j8 = 0; j8 < 8; ++j8) {
            f32x4 v0 = *(const f32x4*)(zp + j8 * 8);
            f32x4 v1 = *(const f32x4*)(zp + j8 * 8 + 4);
            bf16x8 pk;
            pk[0] = f2bf_hw(v0.x); pk[1] = f2bf_hw(v0.y);
            pk[2] = f2bf_hw(v0.z); pk[3] = f2bf_hw(v0.w);
            pk[4] = f2bf_hw(v1.x); pk[5] = f2bf_hw(v1.y);
            pk[6] = f2bf_hw(v1.z); pk[7] = f2bf_hw(v1.w);
            *(bf16x8*)(Zl + b * 1024 + ((ks * 2 + j8 * 16) ^ bx)) = pk;
        }
    }
    __syncthreads();   // Zl ready

    const int rl = lane & 15;            // local row (D col); b in A frag
    const int kq = lane >> 4;            // k-quadrant
    const int zxor = (rl & 7) << 4;
    const int rowLocal = wv * 16 + rl;   // 0..143
    const int rowg = blockIdx.x * 144 + rowLocal;

    const char* wp = (const char*)Wh + (size_t)rowg * (ZD * 4) + kq * 32;

    // rotating in-flight buffer: 16 x f32x4 (64 VGPR), 8 kb outstanding
    f32x4 wd[16];
    #pragma unroll
    for (int i = 0; i < 8; ++i) {
        wd[2 * i]     = *(const f32x4*)(wp + i * 128);
        wd[2 * i + 1] = *(const f32x4*)(wp + i * 128 + 16);
    }

    f32x4 acc0 = {0.f, 0.f, 0.f, 0.f}, acc1 = {0.f, 0.f, 0.f, 0.f};
    #pragma unroll
    for (int kb = 0; kb < 16; ++kb) {
        const int sl = kb & 7;
        const int koff = (kb * 64 + kq * 16) ^ zxor;
        bf16x8 a0 = *(const bf16x8*)(Zl + rl * 1024 + koff);
        bf16x8 a1 = *(const bf16x8*)(Zl + (16 + rl) * 1024 + koff);
        f32x4 lo = wd[2 * sl];
        f32x4 hi = wd[2 * sl + 1];
        bf16x8 bw;
        bw[0] = f2bf_hw(lo.x); bw[1] = f2bf_hw(lo.y);
        bw[2] = f2bf_hw(lo.z); bw[3] = f2bf_hw(lo.w);
        bw[4] = f2bf_hw(hi.x); bw[5] = f2bf_hw(hi.y);
        bw[6] = f2bf_hw(hi.z); bw[7] = f2bf_hw(hi.w);
        acc0 = __builtin_amdgcn_mfma_f32_16x16x32_bf16(a0, bw, acc0, 0, 0, 0);
        acc1 = __builtin_amdgcn_mfma_f32_16x16x32_bf16(a1, bw, acc1, 0, 0, 0);
        if (kb < 8) {
            wd[2 * sl]     = *(const f32x4*)(wp + (kb + 8) * 128);
            wd[2 * sl + 1] = *(const f32x4*)(wp + (kb + 8) * 128 + 16);
        }
    }

    // store to Sl[rowLocal][b] bf16, swizzled byte ^ ((rowLocal&7)<<3)
    {
        const int swz = (rowLocal & 7) << 3;
        s16x4 s0, s1;
        #pragma unroll
        for (int reg = 0; reg < 4; ++reg) {
            s0[reg] = f2bf(acc0[reg]);
            s1[reg] = f2bf(acc1[reg]);
        }
        *(s16x4*)(Sl + rowLocal * 64 + ((kq * 8) ^ swz))      = s0;
        *(s16x4*)(Sl + rowLocal * 64 + ((32 + kq * 8) ^ swz)) = s1;
    }
    __syncthreads();

    // repack phase (512 active threads): thread = (b, oiL)
    if (tid < 512) {
        const int b  = tid >> 4;             // 0..31
        const int oiL = tid & 15;            // 0..15
        const int oi = blockIdx.x * 16 + oiL;
        #pragma unroll
        for (int rs = 0; rs < 9; ++rs) {
            const int rowL = oiL * 9 + rs;
            short sh = *(const short*)(Sl + rowL * 64 +
                                       ((2 * b) ^ ((rowL & 7) << 3)));
            float v = bf2f(sh) + bh[(size_t)oi * 9 + rs];
            wbf[((size_t)(b * 9 + rs)) * OI + oi] = f2bf(v);
        }
    }
}

// ---------------------------------------------------------------------------
// Kernel 3 (v3): conv, BH=2, 256 thr = 4 waves (wave = (hh, o-half)),
// 4x4 fragment blocking per wave (64o x 64p, 64 acc VGPR): per rs only
// 8 wave-b128 reads per kk for 16 MFMAs -> 128 KB LDS/rs/block (was 192).
// W triple-buffered, counted vmcnt(8) + one barrier per rs.  X [4][58][128]
// staged once.  LDS 154 KB -> 1 block/CU.
// ---------------------------------------------------------------------------
__global__ __launch_bounds__(256) void conv_kernel(
    const short* __restrict__ wbf,   // [b][rs][o][i] bf16
    const short* __restrict__ xt,    // [b][h][w][i]  bf16
    float* __restrict__ out)         // [b][o][h][w]  fp32
{
    __shared__ __align__(16) char Xl[XTILE];       // 59392 B
    __shared__ __align__(16) char Wl[3][32768];    // 98304 B
    const int tid  = threadIdx.x;
    const int lane = tid & 63;
    const int wv   = tid >> 6;       // 0..3
    const int og   = wv & 1;         // o-half (64 o)
    const int hh   = wv >> 1;        // output row within block
    const int h0 = blockIdx.x * 2;
    const int b  = blockIdx.y;

    // zero X tile (halo + missing border rows)
    #pragma unroll
    for (int q = 0; q < 15; ++q) {
        int idx = tid + q * 256;
        if (idx < XTILE / 16) ((f32x4*)Xl)[idx] = (f32x4){0.f, 0.f, 0.f, 0.f};
    }
    __syncthreads();

    // stage X rows 0..3 (input hin = h0 + r - 1), pre-swizzled source
    for (int r = 0; r < 4; ++r) {
        int hin = h0 + r - 1;
        if (hin < 0 || hin >= HH) continue;
        const char* src = (const char*)(xt + ((size_t)(b * HH + hin)) * WW * IC);
        char* dstb = Xl + (r * WDIM + 1) * 256;
        for (int it = wv; it < 14; it += 4) {
            int c = it * 64 + lane;
            int u = r * WDIM + 1 + (c >> 4);
            int soff = (c * 16) ^ ((u & 7) << 4);
            gll16(src + soff, dstb + it * 1024);
        }
    }

    // W staging: 8 gll16 per wave per slice (uniform across waves)
    #define STAGE_CW(rs_, buf_)                                                 \
        {                                                                       \
            const char* ws_ = (const char*)(wbf +                               \
                ((size_t)b * NRS + (rs_)) * OI);                                \
            _Pragma("unroll")                                                   \
            for (int it_ = 0; it_ < 8; ++it_) {                                 \
                int c_ = (wv * 8 + it_) * 64 + lane;                            \
                int so_ = (c_ * 16) ^ (((c_ >> 4) & 7) << 4);                   \
                gll16(ws_ + so_, Wl[buf_] + (wv * 8 + it_) * 1024);             \
            }                                                                   \
        }

    STAGE_CW(0, 0);

    f32x4 acc[4][4];   // [af][pf]
    #pragma unroll
    for (int a = 0; a < 4; ++a)
        #pragma unroll
        for (int p = 0; p < 4; ++p) acc[a][p] = (f32x4){0.f, 0.f, 0.f, 0.f};

    const int axor = (lane & 7) << 4;
    int kkoff[4];
    #pragma unroll
    for (int kk = 0; kk < 4; ++kk) kkoff[kk] = kk * 64 + ((lane >> 4) << 4);

    for (int rs = 0; rs < 9; ++rs) {
        if (rs < 8) STAGE_CW(rs + 1, (rs + 1) % 3);
        if (rs == 8) { asm volatile("s_waitcnt vmcnt(0)" ::: "memory"); }
        else         { asm volatile("s_waitcnt vmcnt(8)" ::: "memory"); }
        __builtin_amdgcn_sched_barrier(0);
        __builtin_amdgcn_s_barrier();
        __builtin_amdgcn_sched_barrier(0);

        const char* Wb = Wl[rs % 3];
        const int r = rs / 3, s = rs - 3 * r;
        int ubase[4], bswz[4];
        #pragma unroll
        for (int pf = 0; pf < 4; ++pf) {
            int p = pf * 16 + (lane & 15);
            int pc = p > 55 ? 55 : p;            // clamp garbage lanes
            int uu = (hh + r) * WDIM + pc + s;   // tile row = hh + r
            ubase[pf] = uu * 256;
            bswz[pf] = (uu & 7) << 4;
        }
        #pragma unroll
        for (int kk = 0; kk < 4; ++kk) {
            bf16x8 av[4];
            #pragma unroll
            for (int af = 0; af < 4; ++af)
                av[af] = *(const bf16x8*)(Wb + (og * 64 + af * 16 + (lane & 15)) * 256 +
                                          (kkoff[kk] ^ axor));
            #pragma unroll
            for (int pf = 0; pf < 4; ++pf) {
                bf16x8 bv = *(const bf16x8*)(Xl + ubase[pf] + (kkoff[kk] ^ bswz[pf]));
                #pragma unroll
                for (int af = 0; af < 4; ++af)
                    acc[af][pf] = __builtin_amdgcn_mfma_f32_16x16x32_bf16(
                        av[af], bv, acc[af][pf], 0, 0, 0);
            }
        }
    }
    #undef STAGE_CW

    // epilogue: D col = lane&15 (=p), row = 4*(lane>>4)+reg (=o offset)
    const int pcol = lane & 15;
    const int rowq = lane >> 4;
    const int hO = h0 + hh;
    #pragma unroll
    for (int af = 0; af < 4; ++af) {
        int o0 = og * 64 + af * 16 + rowq * 4;
        #pragma unroll
        for (int pf = 0; pf < 4; ++pf) {
            int p = pf * 16 + pcol;
            if (p < WW) {
                #pragma unroll
                for (int reg = 0; reg < 4; ++reg) {
                    out[(((size_t)b * OC + (o0 + reg)) * HH + hO) * WW + p] = acc[af][pf][reg];
                }
            }
        }
    }
}

extern "C" void kernel_launch(void* const* d_in, const int* in_sizes, int n_in,
                              void* d_out, int out_size, void* d_ws, size_t ws_size,
                              hipStream_t stream) {
    const float* x  = (const float*)d_in[0];   // [32,128,56,56]
    const float* z  = (const float*)d_in[1];   // [32,512]
    const float* Wh = (const float*)d_in[2];   // [147456,512]
    const float* bh = (const float*)d_in[3];   // [147456]
    float* out = (float*)d_out;

    short* wbf = (short*)d_ws;                               // 9,437,184 B
    short* xt  = (short*)((char*)d_ws + 9437184);            // 25,690,112 B

    fused_head_tr_kernel<<<dim3(NHEADBLK + NTRBLK), 576, 0, stream>>>(Wh, z, bh, wbf, x, xt);
    conv_kernel<<<dim3(HH / 2, BB), 256, 0, stream>>>(wbf, xt, out);
}